// Round 1
// baseline (1483.372 us; speedup 1.0000x reference)
//
#include <hip/hip_runtime.h>
#include <cstdint>
#include <cstddef>

typedef __bf16 bf16;
typedef __attribute__((ext_vector_type(8))) __bf16 bf16x8;
typedef __attribute__((ext_vector_type(4))) float f32x4;

#define NB 256
#define NS 128
#define NH 8
#define NDK 128
#define NP 128
#define NDM 1024

static constexpr float kScale = 0.05103103630798287f;  // 1/sqrt(3*128)
static constexpr float kNeg = -1.0e9f;

static __device__ __forceinline__ f32x4 mfma16(bf16x8 a, bf16x8 b, f32x4 c) {
  return __builtin_amdgcn_mfma_f32_16x16x32_bf16(a, b, c, 0, 0, 0);
}

// reduce across the 16 lanes sharing (lane>>4); xor masks 1,2,4,8 stay in-group
static __device__ __forceinline__ float red16_max(float v) {
  v = fmaxf(v, __shfl_xor(v, 1, 64));
  v = fmaxf(v, __shfl_xor(v, 2, 64));
  v = fmaxf(v, __shfl_xor(v, 4, 64));
  v = fmaxf(v, __shfl_xor(v, 8, 64));
  return v;
}
static __device__ __forceinline__ float red16_sum(float v) {
  v += __shfl_xor(v, 1, 64);
  v += __shfl_xor(v, 2, 64);
  v += __shfl_xor(v, 4, 64);
  v += __shfl_xor(v, 8, 64);
  return v;
}

// ---------------- prep: transpose+cast weights, cast/transpose rel tables ---
static __device__ void transpose64(const float* __restrict__ src, bf16* __restrict__ dst,
                                   int rows, int cols, int r0, int c0,
                                   float (*t)[65], int tid) {
  const int tr = tid >> 4, tc = tid & 15;
#pragma unroll
  for (int i = 0; i < 4; i++) {
    int r = tr + i * 16;
    float4 v = *(const float4*)&src[(size_t)(r0 + r) * cols + c0 + tc * 4];
    t[r][tc * 4 + 0] = v.x;
    t[r][tc * 4 + 1] = v.y;
    t[r][tc * 4 + 2] = v.z;
    t[r][tc * 4 + 3] = v.w;
  }
  __syncthreads();
#pragma unroll
  for (int i = 0; i < 4; i++) {
    int c = tr + i * 16;
    union { bf16 o[4]; uint64_t u; } pk;
#pragma unroll
    for (int k2 = 0; k2 < 4; k2++) pk.o[k2] = (bf16)t[tc * 4 + k2][c];
    *(uint64_t*)&dst[(size_t)(c0 + c) * rows + r0 + tc * 4] = pk.u;
  }
}

__global__ __launch_bounds__(256) void prep_kernel(
    const float* __restrict__ Wq, const float* __restrict__ Wk,
    const float* __restrict__ Wv, const float* __restrict__ Wo,
    const float* __restrict__ rel_q, const float* __restrict__ rel_k,
    const float* __restrict__ rel_v,
    bf16* __restrict__ Wtq, bf16* __restrict__ Wtk,
    bf16* __restrict__ Wtv, bf16* __restrict__ Wto,
    bf16* __restrict__ rqb, bf16* __restrict__ rkb, bf16* __restrict__ rvt) {
  __shared__ float t[64][65];
  const int tid = threadIdx.x;
  const int z = blockIdx.z;
  if (z < 4) {
    const float* src = (z == 0) ? Wq : (z == 1) ? Wk : (z == 2) ? Wv : Wo;
    bf16* dst = (z == 0) ? Wtq : (z == 1) ? Wtk : (z == 2) ? Wtv : Wto;
    transpose64(src, dst, NDM, NDM, blockIdx.y * 64, blockIdx.x * 64, t, tid);
  } else if (z == 4) {
    int lb = blockIdx.y * 16 + blockIdx.x;
    if (lb < 32) {
      int hh = lb >> 2, tt = lb & 3;
      transpose64(rel_v + (size_t)hh * NP * NDK, rvt + (size_t)hh * NDK * NP,
                  NP, NDK, (tt >> 1) * 64, (tt & 1) * 64, t, tid);
    }
  } else {
    int lb = blockIdx.y * 16 + blockIdx.x;
    if (lb < 128) {
      size_t base = (size_t)lb * 1024 + (size_t)tid * 4;
      float4 a = *(const float4*)&rel_q[base];
      float4 c = *(const float4*)&rel_k[base];
      union { bf16 o[4]; uint64_t u; } pa, pc;
      pa.o[0] = (bf16)a.x; pa.o[1] = (bf16)a.y; pa.o[2] = (bf16)a.z; pa.o[3] = (bf16)a.w;
      pc.o[0] = (bf16)c.x; pc.o[1] = (bf16)c.y; pc.o[2] = (bf16)c.z; pc.o[3] = (bf16)c.w;
      *(uint64_t*)&rqb[base] = pa.u;
      *(uint64_t*)&rkb[base] = pc.u;
    }
  }
}

// ---------------- projection GEMM: X(f32)[32768,1024] @ Wt^T + b -> bf16 [B,H,S,DK]
__global__ __launch_bounds__(256, 2) void proj_gemm(
    const float* __restrict__ Xq, const float* __restrict__ Xk, const float* __restrict__ Xv,
    const bf16* __restrict__ Wtq, const bf16* __restrict__ Wtk, const bf16* __restrict__ Wtv,
    const float* __restrict__ bq, const float* __restrict__ bk, const float* __restrict__ bv,
    bf16* __restrict__ Oq, bf16* __restrict__ Ok, bf16* __restrict__ Ov) {
  __shared__ __attribute__((aligned(16))) bf16 sA[128][72];
  __shared__ __attribute__((aligned(16))) bf16 sB[128][72];
  const int z = blockIdx.z;
  const float* X = (z == 0) ? Xq : (z == 1) ? Xk : Xv;
  const bf16* Wt = (z == 0) ? Wtq : (z == 1) ? Wtk : Wtv;
  const float* bias = (z == 0) ? bq : (z == 1) ? bk : bv;
  bf16* O = (z == 0) ? Oq : (z == 1) ? Ok : Ov;

  const int M0 = blockIdx.y * 128, N0 = blockIdx.x * 128;
  const int tid = threadIdx.x, lane = tid & 63, w = tid >> 6;
  const int l15 = lane & 15, l4 = lane >> 4;
  const int wm = w >> 1, wn = w & 1;

  f32x4 acc[4][4];
#pragma unroll
  for (int mt = 0; mt < 4; mt++)
#pragma unroll
    for (int nt = 0; nt < 4; nt++) acc[mt][nt] = (f32x4){0.f, 0.f, 0.f, 0.f};

  const int ar = tid >> 4, ac4 = tid & 15;
  const int bn = tid >> 3, bc8 = tid & 7;

  for (int k0 = 0; k0 < NDM; k0 += 64) {
#pragma unroll
    for (int i = 0; i < 8; i++) {
      int rr = ar + i * 16;
      float4 v = *(const float4*)&X[(size_t)(M0 + rr) * NDM + k0 + ac4 * 4];
      union { bf16 o[4]; uint64_t u; } pk;
      pk.o[0] = (bf16)v.x; pk.o[1] = (bf16)v.y; pk.o[2] = (bf16)v.z; pk.o[3] = (bf16)v.w;
      *(uint64_t*)&sA[rr][ac4 * 4] = pk.u;
    }
#pragma unroll
    for (int i = 0; i < 4; i++) {
      int nn = bn + i * 32;
      *(bf16x8*)&sB[nn][bc8 * 8] = *(const bf16x8*)&Wt[(size_t)(N0 + nn) * NDM + k0 + bc8 * 8];
    }
    __syncthreads();
#pragma unroll
    for (int kk = 0; kk < 64; kk += 32) {
      bf16x8 af[4], bfv[4];
#pragma unroll
      for (int mt = 0; mt < 4; mt++)
        af[mt] = *(const bf16x8*)&sA[wm * 64 + mt * 16 + l15][kk + l4 * 8];
#pragma unroll
      for (int nt = 0; nt < 4; nt++)
        bfv[nt] = *(const bf16x8*)&sB[wn * 64 + nt * 16 + l15][kk + l4 * 8];
#pragma unroll
      for (int mt = 0; mt < 4; mt++)
#pragma unroll
        for (int nt = 0; nt < 4; nt++)
          acc[mt][nt] = mfma16(af[mt], bfv[nt], acc[mt][nt]);
    }
    __syncthreads();
  }
#pragma unroll
  for (int mt = 0; mt < 4; mt++) {
#pragma unroll
    for (int nt = 0; nt < 4; nt++) {
      int n = N0 + wn * 64 + nt * 16 + l15;
      float bv_ = bias[n];
      int h = n >> 7, dk = n & 127;
#pragma unroll
      for (int r = 0; r < 4; r++) {
        int m = M0 + wm * 64 + mt * 16 + l4 * 4 + r;
        int b = m >> 7, s = m & 127;
        O[(((size_t)b * NH + h) * NS + s) * NDK + dk] = (bf16)(acc[mt][nt][r] + bv_);
      }
    }
  }
}

// ---------------- V tile transpose: [BH][S][DK] -> [BH][DK][S] (bf16) -------
__global__ __launch_bounds__(256) void vt_kernel(const bf16* __restrict__ Vin,
                                                 bf16* __restrict__ Vt) {
  __shared__ __attribute__((aligned(16))) bf16 t[64][72];
  const size_t base = (size_t)blockIdx.z * (NS * NDK);
  const int r0 = blockIdx.y * 64, c0 = blockIdx.x * 64;
  const int tid = threadIdx.x;
  const int tr = tid >> 3, tc8 = tid & 7;
#pragma unroll
  for (int i = 0; i < 2; i++) {
    int r = tr + i * 32;
    *(bf16x8*)&t[r][tc8 * 8] = *(const bf16x8*)&Vin[base + (size_t)(r0 + r) * NDK + c0 + tc8 * 8];
  }
  __syncthreads();
#pragma unroll
  for (int i = 0; i < 2; i++) {
    int c = tr + i * 32;
    bf16x8 o;
#pragma unroll
    for (int k2 = 0; k2 < 8; k2++) o[k2] = t[tc8 * 8 + k2][c];
    *(bf16x8*)&Vt[base + (size_t)(c0 + c) * NS + r0 + tc8 * 8] = o;
  }
}

// ---------------- attention: one block per (b,h) ----------------------------
__global__ __launch_bounds__(256, 1) void attn_kernel(
    const bf16* __restrict__ Qg, const bf16* __restrict__ Kg, const bf16* __restrict__ Vtg,
    const bf16* __restrict__ relq, const bf16* __restrict__ relk, const bf16* __restrict__ relvT,
    const int* __restrict__ qpos, const int* __restrict__ kvpos,
    bf16* __restrict__ ctx) {
  constexpr int LD = 136;  // +8 bf16 pad: keeps 16B alignment, breaks 32-way banks
  __shared__ __attribute__((aligned(16))) bf16 R0[128 * LD];
  __shared__ __attribute__((aligned(16))) bf16 R1[128 * LD];
  __shared__ __attribute__((aligned(16))) bf16 R2[128 * LD];
  __shared__ __attribute__((aligned(16))) bf16 R3[128 * LD];

  const int bh = blockIdx.x;
  const int b = bh >> 3, h = bh & 7;
  const int tid = threadIdx.x, lane = tid & 63, w = tid >> 6;
  const int l15 = lane & 15, l4 = lane >> 4;
  const int m0 = w * 32;  // this wave owns score rows [m0, m0+32)

  const size_t tb = (size_t)bh * (NS * NDK);
  const bf16* Qp = Qg + tb;
  const bf16* Kp = Kg + tb;
  const bf16* Vp = Vtg + tb;
  const bf16* rq = relq + (size_t)h * NP * NDK;
  const bf16* rk = relk + (size_t)h * NP * NDK;
  const bf16* rv = relvT + (size_t)h * NDK * NP;
  const int* qpp = qpos + (size_t)bh * NS * NS;
  const int* kpp = kvpos + (size_t)bh * NS * NS;

  auto load_tile = [&](bf16* dst, const bf16* src) {
    const int r = tid >> 4, c8 = tid & 15;
#pragma unroll
    for (int i = 0; i < 8; i++) {
      int rr = r + i * 16;
      *(bf16x8*)&dst[rr * LD + c8 * 8] = *(const bf16x8*)&src[rr * 128 + c8 * 8];
    }
  };
  // NT wave GEMM: C[m0+.., :] += A rows (own band) x B^T rows (all 128)
  auto gemmNT = [&](const bf16* A, const bf16* Bm, f32x4 (&acc)[2][8]) {
#pragma unroll
    for (int kk = 0; kk < 128; kk += 32) {
      bf16x8 a0 = *(const bf16x8*)&A[(m0 + l15) * LD + kk + l4 * 8];
      bf16x8 a1 = *(const bf16x8*)&A[(m0 + 16 + l15) * LD + kk + l4 * 8];
#pragma unroll
      for (int nt = 0; nt < 8; nt++) {
        bf16x8 bb = *(const bf16x8*)&Bm[(nt * 16 + l15) * LD + kk + l4 * 8];
        acc[0][nt] = mfma16(a0, bb, acc[0][nt]);
        acc[1][nt] = mfma16(a1, bb, acc[1][nt]);
      }
    }
  };

  // stage 1: Q->R0, K->R1, rel_q->R2
  load_tile(R0, Qp);
  load_tile(R1, Kp);
  load_tile(R2, rq);
  __syncthreads();

  // stage 2a: p2c_raw = rel_q @ K^T (scaled, bf16) -> R3
  {
    f32x4 acc[2][8];
#pragma unroll
    for (int mt = 0; mt < 2; mt++)
#pragma unroll
      for (int nt = 0; nt < 8; nt++) acc[mt][nt] = (f32x4){0.f, 0.f, 0.f, 0.f};
    gemmNT(R2, R1, acc);
#pragma unroll
    for (int mt = 0; mt < 2; mt++)
#pragma unroll
      for (int nt = 0; nt < 8; nt++)
#pragma unroll
        for (int r = 0; r < 4; r++) {
          int pp = m0 + mt * 16 + l4 * 4 + r;
          int j = nt * 16 + l15;
          R3[pp * LD + j] = (bf16)(acc[mt][nt][r] * kScale);
        }
  }
  // stage 2b: c2c held in registers (unscaled)
  f32x4 sc[2][8];
#pragma unroll
  for (int mt = 0; mt < 2; mt++)
#pragma unroll
    for (int nt = 0; nt < 8; nt++) sc[mt][nt] = (f32x4){0.f, 0.f, 0.f, 0.f};
  gemmNT(R0, R1, sc);
  __syncthreads();

  // stage 2c: rel_k -> R2
  load_tile(R2, rk);
  __syncthreads();

  // stage 2d: c2p_raw = Q @ rel_k^T (scaled, bf16) -> R1 (K dead)
  {
    f32x4 acc[2][8];
#pragma unroll
    for (int mt = 0; mt < 2; mt++)
#pragma unroll
      for (int nt = 0; nt < 8; nt++) acc[mt][nt] = (f32x4){0.f, 0.f, 0.f, 0.f};
    gemmNT(R0, R2, acc);
#pragma unroll
    for (int mt = 0; mt < 2; mt++)
#pragma unroll
      for (int nt = 0; nt < 8; nt++)
#pragma unroll
        for (int r = 0; r < 4; r++) {
          int i = m0 + mt * 16 + l4 * 4 + r;
          int pp = nt * 16 + l15;
          R1[i * LD + pp] = (bf16)(acc[mt][nt][r] * kScale);
        }
  }

  // stage 3: gather-add, mask, exact two-stage softmax (matches jax semantics)
  unsigned long long keep = 0ull;
#pragma unroll
  for (int mt = 0; mt < 2; mt++)
#pragma unroll
    for (int nt = 0; nt < 8; nt++)
#pragma unroll
      for (int r = 0; r < 4; r++) {
        int i = m0 + mt * 16 + l4 * 4 + r;
        int j = nt * 16 + l15;
        int qv = qpp[i * NS + j];
        int kv = kpp[i * NS + j];
        float v = sc[mt][nt][r] * kScale + (float)R3[qv * LD + j] + (float)R1[i * LD + kv];
        sc[mt][nt][r] = v;
        if (qv == 0 || i == 0) keep |= 1ull << (mt * 32 + nt * 4 + r);
      }
  float rmx[2][4];
#pragma unroll
  for (int mt = 0; mt < 2; mt++)
#pragma unroll
    for (int r = 0; r < 4; r++) {
      float m = -3.0e38f;
#pragma unroll
      for (int nt = 0; nt < 8; nt++) m = fmaxf(m, sc[mt][nt][r]);
      rmx[mt][r] = red16_max(m);
    }
#pragma unroll
  for (int mt = 0; mt < 2; mt++)
#pragma unroll
    for (int nt = 0; nt < 8; nt++)
#pragma unroll
      for (int r = 0; r < 4; r++) {
        float v = sc[mt][nt][r] - rmx[mt][r];  // pre-mask rowwise max subtract
        if (!((keep >> (mt * 32 + nt * 4 + r)) & 1ull)) v = kNeg;
        sc[mt][nt][r] = v;
      }
  float m2[2][4], inv[2][4];
#pragma unroll
  for (int mt = 0; mt < 2; mt++)
#pragma unroll
    for (int r = 0; r < 4; r++) {
      float m = -3.0e38f;
#pragma unroll
      for (int nt = 0; nt < 8; nt++) m = fmaxf(m, sc[mt][nt][r]);
      m2[mt][r] = red16_max(m);  // softmax-internal max (handles fully-masked rows)
    }
#pragma unroll
  for (int mt = 0; mt < 2; mt++)
#pragma unroll
    for (int nt = 0; nt < 8; nt++)
#pragma unroll
      for (int r = 0; r < 4; r++) sc[mt][nt][r] = __expf(sc[mt][nt][r] - m2[mt][r]);
#pragma unroll
  for (int mt = 0; mt < 2; mt++)
#pragma unroll
    for (int r = 0; r < 4; r++) {
      float s = 0.f;
#pragma unroll
      for (int nt = 0; nt < 8; nt++) s += sc[mt][nt][r];
      inv[mt][r] = 1.0f / red16_sum(s);
    }
#pragma unroll
  for (int mt = 0; mt < 2; mt++)
#pragma unroll
    for (int nt = 0; nt < 8; nt++)
#pragma unroll
      for (int r = 0; r < 4; r++) sc[mt][nt][r] *= inv[mt][r];
  __syncthreads();  // all waves done reading R3 (p2c) / R1 (c2p)

  // stage 4a: probs -> R3; V^T -> R0; rel_v^T -> R1
#pragma unroll
  for (int mt = 0; mt < 2; mt++)
#pragma unroll
    for (int nt = 0; nt < 8; nt++)
#pragma unroll
      for (int r = 0; r < 4; r++) {
        int i = m0 + mt * 16 + l4 * 4 + r;
        int j = nt * 16 + l15;
        R3[i * LD + j] = (bf16)sc[mt][nt][r];
      }
  load_tile(R0, Vp);
  load_tile(R1, rv);
  __syncthreads();

  // stage 4b: pos_ctx_raw = P @ rel_v -> R2 ; ctx = P @ V + gather(pos_ctx_raw)
  {
    f32x4 acc2[2][8];
#pragma unroll
    for (int mt = 0; mt < 2; mt++)
#pragma unroll
      for (int nt = 0; nt < 8; nt++) acc2[mt][nt] = (f32x4){0.f, 0.f, 0.f, 0.f};
    gemmNT(R3, R1, acc2);
#pragma unroll
    for (int mt = 0; mt < 2; mt++)
#pragma unroll
      for (int nt = 0; nt < 8; nt++)
#pragma unroll
        for (int r = 0; r < 4; r++) {
          int i = m0 + mt * 16 + l4 * 4 + r;
          int d = nt * 16 + l15;
          R2[i * LD + d] = (bf16)acc2[mt][nt][r];
        }
  }
  {
    f32x4 acc1[2][8];
#pragma unroll
    for (int mt = 0; mt < 2; mt++)
#pragma unroll
      for (int nt = 0; nt < 8; nt++) acc1[mt][nt] = (f32x4){0.f, 0.f, 0.f, 0.f};
    gemmNT(R3, R0, acc1);
#pragma unroll
    for (int mt = 0; mt < 2; mt++)
#pragma unroll
      for (int nt = 0; nt < 8; nt++)
#pragma unroll
        for (int r = 0; r < 4; r++) {
          int i = m0 + mt * 16 + l4 * 4 + r;
          int d = nt * 16 + l15;
          int kv = kpp[i * NS + d];
          float v = acc1[mt][nt][r] + (float)R2[i * LD + kv];
          ctx[(((size_t)b * NS + i) * NH + h) * NDK + d] = (bf16)v;
        }
  }
}

// ---------------- output GEMM: ctx(bf16)[32768,1024] @ Wo^T + bo -> f32 -----
__global__ __launch_bounds__(256, 2) void out_gemm(
    const bf16* __restrict__ Ax, const bf16* __restrict__ Wt,
    const float* __restrict__ bias, float* __restrict__ Out) {
  __shared__ __attribute__((aligned(16))) bf16 sA[128][72];
  __shared__ __attribute__((aligned(16))) bf16 sB[128][72];
  const int M0 = blockIdx.y * 128, N0 = blockIdx.x * 128;
  const int tid = threadIdx.x, lane = tid & 63, w = tid >> 6;
  const int l15 = lane & 15, l4 = lane >> 4;
  const int wm = w >> 1, wn = w & 1;

  f32x4 acc[4][4];
#pragma unroll
  for (int mt = 0; mt < 4; mt++)
#pragma unroll
    for (int nt = 0; nt < 4; nt++) acc[mt][nt] = (f32x4){0.f, 0.f, 0.f, 0.f};

  const int an = tid >> 3, ac8 = tid & 7;
  for (int k0 = 0; k0 < NDM; k0 += 64) {
#pragma unroll
    for (int i = 0; i < 4; i++) {
      int rr = an + i * 32;
      *(bf16x8*)&sA[rr][ac8 * 8] = *(const bf16x8*)&Ax[(size_t)(M0 + rr) * NDM + k0 + ac8 * 8];
      *(bf16x8*)&sB[rr][ac8 * 8] = *(const bf16x8*)&Wt[(size_t)(N0 + rr) * NDM + k0 + ac8 * 8];
    }
    __syncthreads();
#pragma unroll
    for (int kk = 0; kk < 64; kk += 32) {
      bf16x8 af[4], bfv[4];
#pragma unroll
      for (int mt = 0; mt < 4; mt++)
        af[mt] = *(const bf16x8*)&sA[wm * 64 + mt * 16 + l15][kk + l4 * 8];
#pragma unroll
      for (int nt = 0; nt < 4; nt++)
        bfv[nt] = *(const bf16x8*)&sB[wn * 64 + nt * 16 + l15][kk + l4 * 8];
#pragma unroll
      for (int mt = 0; mt < 4; mt++)
#pragma unroll
        for (int nt = 0; nt < 4; nt++)
          acc[mt][nt] = mfma16(af[mt], bfv[nt], acc[mt][nt]);
    }
    __syncthreads();
  }
#pragma unroll
  for (int mt = 0; mt < 4; mt++) {
#pragma unroll
    for (int nt = 0; nt < 4; nt++) {
      int n = N0 + wn * 64 + nt * 16 + l15;
      float bv_ = bias[n];
#pragma unroll
      for (int r = 0; r < 4; r++) {
        int m = M0 + wm * 64 + mt * 16 + l4 * 4 + r;
        Out[(size_t)m * NDM + n] = acc[mt][nt][r] + bv_;
      }
    }
  }
}

extern "C" void kernel_launch(void* const* d_in, const int* in_sizes, int n_in,
                              void* d_out, int out_size, void* d_ws, size_t ws_size,
                              hipStream_t stream) {
  const float* query = (const float*)d_in[0];
  const float* key   = (const float*)d_in[1];
  const float* value = (const float*)d_in[2];
  const int* qpos    = (const int*)d_in[3];
  const int* kvpos   = (const int*)d_in[4];
  const float* rel_q = (const float*)d_in[5];
  const float* rel_k = (const float*)d_in[6];
  const float* rel_v = (const float*)d_in[7];
  const float* Wq = (const float*)d_in[8];
  const float* bq = (const float*)d_in[9];
  const float* Wk = (const float*)d_in[10];
  const float* bk = (const float*)d_in[11];
  const float* Wv = (const float*)d_in[12];
  const float* bv = (const float*)d_in[13];
  const float* Wo = (const float*)d_in[14];
  const float* bo = (const float*)d_in[15];
  float* out = (float*)d_out;

  char* p = (char*)d_ws;
  size_t off = 0;
  auto take = [&](size_t n) {
    char* r = p + off;
    off += (n + 255) & ~(size_t)255;
    return r;
  };
  bf16* Wtq = (bf16*)take((size_t)NDM * NDM * 2);
  bf16* Wtk = (bf16*)take((size_t)NDM * NDM * 2);
  bf16* Wtv = (bf16*)take((size_t)NDM * NDM * 2);
  bf16* Wto = (bf16*)take((size_t)NDM * NDM * 2);
  bf16* rqb = (bf16*)take((size_t)NH * NP * NDK * 2);
  bf16* rkb = (bf16*)take((size_t)NH * NP * NDK * 2);
  bf16* rvt = (bf16*)take((size_t)NH * NDK * NP * 2);
  const size_t big = (size_t)NB * NH * NS * NDK * 2;  // 64 MiB
  bf16* qws  = (bf16*)take(big);
  bf16* kws  = (bf16*)take(big);
  bf16* vws  = (bf16*)take(big);
  bf16* vtws = (bf16*)take(big);
  bf16* ctxw = (bf16*)take(big);

  hipLaunchKernelGGL(prep_kernel, dim3(16, 16, 6), dim3(256), 0, stream,
                     Wq, Wk, Wv, Wo, rel_q, rel_k, rel_v,
                     Wtq, Wtk, Wtv, Wto, rqb, rkb, rvt);
  hipLaunchKernelGGL(proj_gemm, dim3(8, 256, 3), dim3(256), 0, stream,
                     query, key, value, Wtq, Wtk, Wtv, bq, bk, bv, qws, kws, vws);
  hipLaunchKernelGGL(vt_kernel, dim3(2, 2, NB * NH), dim3(256), 0, stream, vws, vtws);
  hipLaunchKernelGGL(attn_kernel, dim3(NB * NH), dim3(256), 0, stream,
                     qws, kws, vtws, rqb, rkb, rvt, qpos, kvpos, ctxw);
  hipLaunchKernelGGL(out_gemm, dim3(8, 256), dim3(256), 0, stream, ctxw, Wto, bo, out);
}

// Round 2
// 1209.646 us; speedup vs baseline: 1.2263x; 1.2263x over previous
//
#include <hip/hip_runtime.h>
#include <cstdint>
#include <cstddef>

typedef __bf16 bf16;
typedef __attribute__((ext_vector_type(8))) __bf16 bf16x8;
typedef __attribute__((ext_vector_type(4))) float f32x4;

#define NB 256
#define NS 128
#define NH 8
#define NDK 128
#define NP 128
#define NDM 1024

static constexpr float kScale = 0.05103103630798287f;  // 1/sqrt(3*128)
static constexpr float kNeg = -1.0e9f;

static __device__ __forceinline__ f32x4 mfma16(bf16x8 a, bf16x8 b, f32x4 c) {
  return __builtin_amdgcn_mfma_f32_16x16x32_bf16(a, b, c, 0, 0, 0);
}

// async global->LDS, 16B per lane; LDS dest is wave-uniform base + lane*16
static __device__ __forceinline__ void gld_lds16(const bf16* g, bf16* l) {
  __builtin_amdgcn_global_load_lds(
      (const __attribute__((address_space(1))) void*)g,
      (__attribute__((address_space(3))) void*)l, 16, 0, 0);
}

// reduce across the 16 lanes sharing (lane>>4)
static __device__ __forceinline__ float red16_max(float v) {
  v = fmaxf(v, __shfl_xor(v, 1, 64));
  v = fmaxf(v, __shfl_xor(v, 2, 64));
  v = fmaxf(v, __shfl_xor(v, 4, 64));
  v = fmaxf(v, __shfl_xor(v, 8, 64));
  return v;
}
static __device__ __forceinline__ float red16_sum(float v) {
  v += __shfl_xor(v, 1, 64);
  v += __shfl_xor(v, 2, 64);
  v += __shfl_xor(v, 4, 64);
  v += __shfl_xor(v, 8, 64);
  return v;
}

// ---------------- prep: transpose+cast weights, cast/transpose rel tables ---
static __device__ void transpose64(const float* __restrict__ src, bf16* __restrict__ dst,
                                   int rows, int cols, int r0, int c0,
                                   float (*t)[65], int tid) {
  const int tr = tid >> 4, tc = tid & 15;
#pragma unroll
  for (int i = 0; i < 4; i++) {
    int r = tr + i * 16;
    float4 v = *(const float4*)&src[(size_t)(r0 + r) * cols + c0 + tc * 4];
    t[r][tc * 4 + 0] = v.x;
    t[r][tc * 4 + 1] = v.y;
    t[r][tc * 4 + 2] = v.z;
    t[r][tc * 4 + 3] = v.w;
  }
  __syncthreads();
#pragma unroll
  for (int i = 0; i < 4; i++) {
    int c = tr + i * 16;
    union { bf16 o[4]; uint64_t u; } pk;
#pragma unroll
    for (int k2 = 0; k2 < 4; k2++) pk.o[k2] = (bf16)t[tc * 4 + k2][c];
    *(uint64_t*)&dst[(size_t)(c0 + c) * rows + r0 + tc * 4] = pk.u;
  }
}

__global__ __launch_bounds__(256) void prep_kernel(
    const float* __restrict__ Wq, const float* __restrict__ Wk,
    const float* __restrict__ Wv, const float* __restrict__ Wo,
    const float* __restrict__ rel_q, const float* __restrict__ rel_k,
    const float* __restrict__ rel_v,
    bf16* __restrict__ Wtq, bf16* __restrict__ Wtk,
    bf16* __restrict__ Wtv, bf16* __restrict__ Wto,
    bf16* __restrict__ rqb, bf16* __restrict__ rkb, bf16* __restrict__ rvt) {
  __shared__ float t[64][65];
  const int tid = threadIdx.x;
  const int z = blockIdx.z;
  if (z < 4) {
    const float* src = (z == 0) ? Wq : (z == 1) ? Wk : (z == 2) ? Wv : Wo;
    bf16* dst = (z == 0) ? Wtq : (z == 1) ? Wtk : (z == 2) ? Wtv : Wto;
    transpose64(src, dst, NDM, NDM, blockIdx.y * 64, blockIdx.x * 64, t, tid);
  } else if (z == 4) {
    int lb = blockIdx.y * 16 + blockIdx.x;
    if (lb < 32) {
      int hh = lb >> 2, tt = lb & 3;
      transpose64(rel_v + (size_t)hh * NP * NDK, rvt + (size_t)hh * NDK * NP,
                  NP, NDK, (tt >> 1) * 64, (tt & 1) * 64, t, tid);
    }
  } else {
    int lb = blockIdx.y * 16 + blockIdx.x;
    if (lb < 128) {
      size_t base = (size_t)lb * 1024 + (size_t)tid * 4;
      float4 a = *(const float4*)&rel_q[base];
      float4 c = *(const float4*)&rel_k[base];
      union { bf16 o[4]; uint64_t u; } pa, pc;
      pa.o[0] = (bf16)a.x; pa.o[1] = (bf16)a.y; pa.o[2] = (bf16)a.z; pa.o[3] = (bf16)a.w;
      pc.o[0] = (bf16)c.x; pc.o[1] = (bf16)c.y; pc.o[2] = (bf16)c.z; pc.o[3] = (bf16)c.w;
      *(uint64_t*)&rqb[base] = pa.u;
      *(uint64_t*)&rkb[base] = pc.u;
    }
  }
}

// ---------------- cast: f32 [32768,1024] -> bf16 ----------------------------
__global__ __launch_bounds__(256) void cast_kernel(
    const float* __restrict__ x0, const float* __restrict__ x1,
    const float* __restrict__ x2,
    bf16* __restrict__ y0, bf16* __restrict__ y1, bf16* __restrict__ y2) {
  const int z = blockIdx.z;
  const float* x = (z == 0) ? x0 : (z == 1) ? x1 : x2;
  bf16* y = (z == 0) ? y0 : (z == 1) ? y1 : y2;
  size_t i = ((size_t)blockIdx.x * 256 + threadIdx.x) * 8;
  float4 a = *(const float4*)&x[i];
  float4 b = *(const float4*)&x[i + 4];
  union { bf16 o[8]; bf16x8 v; } u;
  u.o[0] = (bf16)a.x; u.o[1] = (bf16)a.y; u.o[2] = (bf16)a.z; u.o[3] = (bf16)a.w;
  u.o[4] = (bf16)b.x; u.o[5] = (bf16)b.y; u.o[6] = (bf16)b.z; u.o[7] = (bf16)b.w;
  *(bf16x8*)&y[i] = u.v;
}

// ---------------- m97-style GEMM: A(bf16)[M,1024] @ Wt[N,1024]^T ------------
// proj epilogue: +bias, bf16 out scattered to [B,H,S,DK]
__global__ __launch_bounds__(256) void proj_gemm(
    const bf16* __restrict__ Xq, const bf16* __restrict__ Xk, const bf16* __restrict__ Xv,
    const bf16* __restrict__ Wtq, const bf16* __restrict__ Wtk, const bf16* __restrict__ Wtv,
    const float* __restrict__ bq, const float* __restrict__ bk, const float* __restrict__ bv,
    bf16* __restrict__ Oq, bf16* __restrict__ Ok, bf16* __restrict__ Ov) {
  __shared__ __attribute__((aligned(16))) bf16 sA[128 * 64];
  __shared__ __attribute__((aligned(16))) bf16 sB[128 * 64];
  const int z = blockIdx.z;
  const bf16* X = (z == 0) ? Xq : (z == 1) ? Xk : Xv;
  const bf16* Wt = (z == 0) ? Wtq : (z == 1) ? Wtk : Wtv;
  const float* bias = (z == 0) ? bq : (z == 1) ? bk : bv;
  bf16* O = (z == 0) ? Oq : (z == 1) ? Ok : Ov;

  const int M0 = blockIdx.y * 128, N0 = blockIdx.x * 128;
  const int tid = threadIdx.x, lane = tid & 63, w = tid >> 6;
  const int l15 = lane & 15, l4 = lane >> 4;
  const int wm = w >> 1, wn = w & 1;

  f32x4 acc[4][4];
#pragma unroll
  for (int mt = 0; mt < 4; mt++)
#pragma unroll
    for (int nt = 0; nt < 4; nt++) acc[mt][nt] = (f32x4){0.f, 0.f, 0.f, 0.f};

  // staging: wave w owns chunks w*4..w*4+3; chunk = 8 rows x 64 cols = 1KB
  const int lr = lane >> 3, lc = (lane & 7) * 8;
  const bf16* ap[4];
  const bf16* bp[4];
#pragma unroll
  for (int i = 0; i < 4; i++) {
    int row = w * 32 + i * 8 + lr;
    ap[i] = X + (size_t)(M0 + row) * NDM + lc;
    bp[i] = Wt + (size_t)(N0 + row) * NDM + lc;
  }

  for (int k0 = 0; k0 < NDM; k0 += 64) {
#pragma unroll
    for (int i = 0; i < 4; i++) {
      int chunk = w * 4 + i;
      gld_lds16(ap[i], sA + chunk * 512);
      gld_lds16(bp[i], sB + chunk * 512);
      ap[i] += 64;
      bp[i] += 64;
    }
    __syncthreads();
#pragma unroll
    for (int kk = 0; kk < 64; kk += 32) {
      bf16x8 af[4], bfv[4];
#pragma unroll
      for (int mt = 0; mt < 4; mt++)
        af[mt] = *(const bf16x8*)&sA[(wm * 64 + mt * 16 + l15) * 64 + kk + l4 * 8];
#pragma unroll
      for (int nt = 0; nt < 4; nt++)
        bfv[nt] = *(const bf16x8*)&sB[(wn * 64 + nt * 16 + l15) * 64 + kk + l4 * 8];
#pragma unroll
      for (int mt = 0; mt < 4; mt++)
#pragma unroll
        for (int nt = 0; nt < 4; nt++)
          acc[mt][nt] = mfma16(af[mt], bfv[nt], acc[mt][nt]);
    }
    __syncthreads();
  }
#pragma unroll
  for (int mt = 0; mt < 4; mt++) {
#pragma unroll
    for (int nt = 0; nt < 4; nt++) {
      int n = N0 + wn * 64 + nt * 16 + l15;
      float bv_ = bias[n];
      int h = n >> 7, dk = n & 127;
#pragma unroll
      for (int r = 0; r < 4; r++) {
        int m = M0 + wm * 64 + mt * 16 + l4 * 4 + r;
        int b = m >> 7, s = m & 127;
        O[(((size_t)b * NH + h) * NS + s) * NDK + dk] = (bf16)(acc[mt][nt][r] + bv_);
      }
    }
  }
}

// out epilogue: +bias, f32 row-major [M,1024]
__global__ __launch_bounds__(256) void out_gemm(
    const bf16* __restrict__ Ax, const bf16* __restrict__ Wt,
    const float* __restrict__ bias, float* __restrict__ Out) {
  __shared__ __attribute__((aligned(16))) bf16 sA[128 * 64];
  __shared__ __attribute__((aligned(16))) bf16 sB[128 * 64];
  const int M0 = blockIdx.y * 128, N0 = blockIdx.x * 128;
  const int tid = threadIdx.x, lane = tid & 63, w = tid >> 6;
  const int l15 = lane & 15, l4 = lane >> 4;
  const int wm = w >> 1, wn = w & 1;

  f32x4 acc[4][4];
#pragma unroll
  for (int mt = 0; mt < 4; mt++)
#pragma unroll
    for (int nt = 0; nt < 4; nt++) acc[mt][nt] = (f32x4){0.f, 0.f, 0.f, 0.f};

  const int lr = lane >> 3, lc = (lane & 7) * 8;
  const bf16* ap[4];
  const bf16* bp[4];
#pragma unroll
  for (int i = 0; i < 4; i++) {
    int row = w * 32 + i * 8 + lr;
    ap[i] = Ax + (size_t)(M0 + row) * NDM + lc;
    bp[i] = Wt + (size_t)(N0 + row) * NDM + lc;
  }

  for (int k0 = 0; k0 < NDM; k0 += 64) {
#pragma unroll
    for (int i = 0; i < 4; i++) {
      int chunk = w * 4 + i;
      gld_lds16(ap[i], sA + chunk * 512);
      gld_lds16(bp[i], sB + chunk * 512);
      ap[i] += 64;
      bp[i] += 64;
    }
    __syncthreads();
#pragma unroll
    for (int kk = 0; kk < 64; kk += 32) {
      bf16x8 af[4], bfv[4];
#pragma unroll
      for (int mt = 0; mt < 4; mt++)
        af[mt] = *(const bf16x8*)&sA[(wm * 64 + mt * 16 + l15) * 64 + kk + l4 * 8];
#pragma unroll
      for (int nt = 0; nt < 4; nt++)
        bfv[nt] = *(const bf16x8*)&sB[(wn * 64 + nt * 16 + l15) * 64 + kk + l4 * 8];
#pragma unroll
      for (int mt = 0; mt < 4; mt++)
#pragma unroll
        for (int nt = 0; nt < 4; nt++)
          acc[mt][nt] = mfma16(af[mt], bfv[nt], acc[mt][nt]);
    }
    __syncthreads();
  }
#pragma unroll
  for (int mt = 0; mt < 4; mt++) {
#pragma unroll
    for (int nt = 0; nt < 4; nt++) {
      int n = N0 + wn * 64 + nt * 16 + l15;
      float bv_ = bias[n];
#pragma unroll
      for (int r = 0; r < 4; r++) {
        int m = M0 + wm * 64 + mt * 16 + l4 * 4 + r;
        Out[(size_t)m * NDM + n] = acc[mt][nt][r] + bv_;
      }
    }
  }
}

// ---------------- V tile transpose: [BH][S][DK] -> [BH][DK][S] (bf16) -------
__global__ __launch_bounds__(256) void vt_kernel(const bf16* __restrict__ Vin,
                                                 bf16* __restrict__ Vt) {
  __shared__ __attribute__((aligned(16))) bf16 t[64][72];
  const size_t base = (size_t)blockIdx.z * (NS * NDK);
  const int r0 = blockIdx.y * 64, c0 = blockIdx.x * 64;
  const int tid = threadIdx.x;
  const int tr = tid >> 3, tc8 = tid & 7;
#pragma unroll
  for (int i = 0; i < 2; i++) {
    int r = tr + i * 32;
    *(bf16x8*)&t[r][tc8 * 8] = *(const bf16x8*)&Vin[base + (size_t)(r0 + r) * NDK + c0 + tc8 * 8];
  }
  __syncthreads();
#pragma unroll
  for (int i = 0; i < 2; i++) {
    int c = tr + i * 32;
    bf16x8 o;
#pragma unroll
    for (int k2 = 0; k2 < 8; k2++) o[k2] = t[tc8 * 8 + k2][c];
    *(bf16x8*)&Vt[base + (size_t)(c0 + c) * NS + r0 + tc8 * 8] = o;
  }
}

// ---------------- attention: one block per (b,h) ----------------------------
__global__ __launch_bounds__(256, 1) void attn_kernel(
    const bf16* __restrict__ Qg, const bf16* __restrict__ Kg, const bf16* __restrict__ Vtg,
    const bf16* __restrict__ relq, const bf16* __restrict__ relk, const bf16* __restrict__ relvT,
    const int* __restrict__ qpos, const int* __restrict__ kvpos,
    bf16* __restrict__ ctx) {
  constexpr int LD = 136;
  __shared__ __attribute__((aligned(16))) bf16 R0[128 * LD];
  __shared__ __attribute__((aligned(16))) bf16 R1[128 * LD];
  __shared__ __attribute__((aligned(16))) bf16 R2[128 * LD];
  __shared__ __attribute__((aligned(16))) bf16 R3[128 * LD];

  const int bh = blockIdx.x;
  const int b = bh >> 3, h = bh & 7;
  const int tid = threadIdx.x, lane = tid & 63, w = tid >> 6;
  const int l15 = lane & 15, l4 = lane >> 4;
  const int m0 = w * 32;

  const size_t tb = (size_t)bh * (NS * NDK);
  const bf16* Qp = Qg + tb;
  const bf16* Kp = Kg + tb;
  const bf16* Vp = Vtg + tb;
  const bf16* rq = relq + (size_t)h * NP * NDK;
  const bf16* rk = relk + (size_t)h * NP * NDK;
  const bf16* rv = relvT + (size_t)h * NDK * NP;
  const int* qpp = qpos + (size_t)bh * NS * NS;
  const int* kpp = kvpos + (size_t)bh * NS * NS;

  auto load_tile = [&](bf16* dst, const bf16* src) {
    const int r = tid >> 4, c8 = tid & 15;
#pragma unroll
    for (int i = 0; i < 8; i++) {
      int rr = r + i * 16;
      *(bf16x8*)&dst[rr * LD + c8 * 8] = *(const bf16x8*)&src[rr * 128 + c8 * 8];
    }
  };
  auto gemmNT = [&](const bf16* A, const bf16* Bm, f32x4 (&acc)[2][8]) {
#pragma unroll
    for (int kk = 0; kk < 128; kk += 32) {
      bf16x8 a0 = *(const bf16x8*)&A[(m0 + l15) * LD + kk + l4 * 8];
      bf16x8 a1 = *(const bf16x8*)&A[(m0 + 16 + l15) * LD + kk + l4 * 8];
#pragma unroll
      for (int nt = 0; nt < 8; nt++) {
        bf16x8 bb = *(const bf16x8*)&Bm[(nt * 16 + l15) * LD + kk + l4 * 8];
        acc[0][nt] = mfma16(a0, bb, acc[0][nt]);
        acc[1][nt] = mfma16(a1, bb, acc[1][nt]);
      }
    }
  };

  load_tile(R0, Qp);
  load_tile(R1, Kp);
  load_tile(R2, rq);
  __syncthreads();

  {
    f32x4 acc[2][8];
#pragma unroll
    for (int mt = 0; mt < 2; mt++)
#pragma unroll
      for (int nt = 0; nt < 8; nt++) acc[mt][nt] = (f32x4){0.f, 0.f, 0.f, 0.f};
    gemmNT(R2, R1, acc);
#pragma unroll
    for (int mt = 0; mt < 2; mt++)
#pragma unroll
      for (int nt = 0; nt < 8; nt++)
#pragma unroll
        for (int r = 0; r < 4; r++) {
          int pp = m0 + mt * 16 + l4 * 4 + r;
          int j = nt * 16 + l15;
          R3[pp * LD + j] = (bf16)(acc[mt][nt][r] * kScale);
        }
  }
  f32x4 sc[2][8];
#pragma unroll
  for (int mt = 0; mt < 2; mt++)
#pragma unroll
    for (int nt = 0; nt < 8; nt++) sc[mt][nt] = (f32x4){0.f, 0.f, 0.f, 0.f};
  gemmNT(R0, R1, sc);
  __syncthreads();

  load_tile(R2, rk);
  __syncthreads();

  {
    f32x4 acc[2][8];
#pragma unroll
    for (int mt = 0; mt < 2; mt++)
#pragma unroll
      for (int nt = 0; nt < 8; nt++) acc[mt][nt] = (f32x4){0.f, 0.f, 0.f, 0.f};
    gemmNT(R0, R2, acc);
#pragma unroll
    for (int mt = 0; mt < 2; mt++)
#pragma unroll
      for (int nt = 0; nt < 8; nt++)
#pragma unroll
        for (int r = 0; r < 4; r++) {
          int i = m0 + mt * 16 + l4 * 4 + r;
          int pp = nt * 16 + l15;
          R1[i * LD + pp] = (bf16)(acc[mt][nt][r] * kScale);
        }
  }

  unsigned long long keep = 0ull;
#pragma unroll
  for (int mt = 0; mt < 2; mt++)
#pragma unroll
    for (int nt = 0; nt < 8; nt++)
#pragma unroll
      for (int r = 0; r < 4; r++) {
        int i = m0 + mt * 16 + l4 * 4 + r;
        int j = nt * 16 + l15;
        int qv = qpp[i * NS + j];
        int kv = kpp[i * NS + j];
        float v = sc[mt][nt][r] * kScale + (float)R3[qv * LD + j] + (float)R1[i * LD + kv];
        sc[mt][nt][r] = v;
        if (qv == 0 || i == 0) keep |= 1ull << (mt * 32 + nt * 4 + r);
      }
  float rmx[2][4];
#pragma unroll
  for (int mt = 0; mt < 2; mt++)
#pragma unroll
    for (int r = 0; r < 4; r++) {
      float m = -3.0e38f;
#pragma unroll
      for (int nt = 0; nt < 8; nt++) m = fmaxf(m, sc[mt][nt][r]);
      rmx[mt][r] = red16_max(m);
    }
#pragma unroll
  for (int mt = 0; mt < 2; mt++)
#pragma unroll
    for (int nt = 0; nt < 8; nt++)
#pragma unroll
      for (int r = 0; r < 4; r++) {
        float v = sc[mt][nt][r] - rmx[mt][r];
        if (!((keep >> (mt * 32 + nt * 4 + r)) & 1ull)) v = kNeg;
        sc[mt][nt][r] = v;
      }
  float m2[2][4], inv[2][4];
#pragma unroll
  for (int mt = 0; mt < 2; mt++)
#pragma unroll
    for (int r = 0; r < 4; r++) {
      float m = -3.0e38f;
#pragma unroll
      for (int nt = 0; nt < 8; nt++) m = fmaxf(m, sc[mt][nt][r]);
      m2[mt][r] = red16_max(m);
    }
#pragma unroll
  for (int mt = 0; mt < 2; mt++)
#pragma unroll
    for (int nt = 0; nt < 8; nt++)
#pragma unroll
      for (int r = 0; r < 4; r++) sc[mt][nt][r] = __expf(sc[mt][nt][r] - m2[mt][r]);
#pragma unroll
  for (int mt = 0; mt < 2; mt++)
#pragma unroll
    for (int r = 0; r < 4; r++) {
      float s = 0.f;
#pragma unroll
      for (int nt = 0; nt < 8; nt++) s += sc[mt][nt][r];
      inv[mt][r] = 1.0f / red16_sum(s);
    }
#pragma unroll
  for (int mt = 0; mt < 2; mt++)
#pragma unroll
    for (int nt = 0; nt < 8; nt++)
#pragma unroll
      for (int r = 0; r < 4; r++) sc[mt][nt][r] *= inv[mt][r];
  __syncthreads();

#pragma unroll
  for (int mt = 0; mt < 2; mt++)
#pragma unroll
    for (int nt = 0; nt < 8; nt++)
#pragma unroll
      for (int r = 0; r < 4; r++) {
        int i = m0 + mt * 16 + l4 * 4 + r;
        int j = nt * 16 + l15;
        R3[i * LD + j] = (bf16)sc[mt][nt][r];
      }
  load_tile(R0, Vp);
  load_tile(R1, rv);
  __syncthreads();

  {
    f32x4 acc2[2][8];
#pragma unroll
    for (int mt = 0; mt < 2; mt++)
#pragma unroll
      for (int nt = 0; nt < 8; nt++) acc2[mt][nt] = (f32x4){0.f, 0.f, 0.f, 0.f};
    gemmNT(R3, R1, acc2);
#pragma unroll
    for (int mt = 0; mt < 2; mt++)
#pragma unroll
      for (int nt = 0; nt < 8; nt++)
#pragma unroll
        for (int r = 0; r < 4; r++) {
          int i = m0 + mt * 16 + l4 * 4 + r;
          int d = nt * 16 + l15;
          R2[i * LD + d] = (bf16)acc2[mt][nt][r];
        }
  }
  {
    f32x4 acc1[2][8];
#pragma unroll
    for (int mt = 0; mt < 2; mt++)
#pragma unroll
      for (int nt = 0; nt < 8; nt++) acc1[mt][nt] = (f32x4){0.f, 0.f, 0.f, 0.f};
    gemmNT(R3, R0, acc1);
#pragma unroll
    for (int mt = 0; mt < 2; mt++)
#pragma unroll
      for (int nt = 0; nt < 8; nt++)
#pragma unroll
        for (int r = 0; r < 4; r++) {
          int i = m0 + mt * 16 + l4 * 4 + r;
          int d = nt * 16 + l15;
          int kv = kpp[i * NS + d];
          float v = acc1[mt][nt][r] + (float)R2[i * LD + kv];
          ctx[(((size_t)b * NS + i) * NH + h) * NDK + d] = (bf16)v;
        }
  }
}

extern "C" void kernel_launch(void* const* d_in, const int* in_sizes, int n_in,
                              void* d_out, int out_size, void* d_ws, size_t ws_size,
                              hipStream_t stream) {
  const float* query = (const float*)d_in[0];
  const float* key   = (const float*)d_in[1];
  const float* value = (const float*)d_in[2];
  const int* qpos    = (const int*)d_in[3];
  const int* kvpos   = (const int*)d_in[4];
  const float* rel_q = (const float*)d_in[5];
  const float* rel_k = (const float*)d_in[6];
  const float* rel_v = (const float*)d_in[7];
  const float* Wq = (const float*)d_in[8];
  const float* bq = (const float*)d_in[9];
  const float* Wk = (const float*)d_in[10];
  const float* bk = (const float*)d_in[11];
  const float* Wv = (const float*)d_in[12];
  const float* bv = (const float*)d_in[13];
  const float* Wo = (const float*)d_in[14];
  const float* bo = (const float*)d_in[15];
  float* out = (float*)d_out;

  char* p = (char*)d_ws;
  size_t off = 0;
  auto take = [&](size_t n) {
    char* r = p + off;
    off += (n + 255) & ~(size_t)255;
    return r;
  };
  bf16* Wtq = (bf16*)take((size_t)NDM * NDM * 2);
  bf16* Wtk = (bf16*)take((size_t)NDM * NDM * 2);
  bf16* Wtv = (bf16*)take((size_t)NDM * NDM * 2);
  bf16* Wto = (bf16*)take((size_t)NDM * NDM * 2);
  bf16* rqb = (bf16*)take((size_t)NH * NP * NDK * 2);
  bf16* rkb = (bf16*)take((size_t)NH * NP * NDK * 2);
  bf16* rvt = (bf16*)take((size_t)NH * NDK * NP * 2);
  const size_t big = (size_t)NB * NH * NS * NDK * 2;  // 64 MiB
  bf16* qws  = (bf16*)take(big);
  bf16* kws  = (bf16*)take(big);
  bf16* vws  = (bf16*)take(big);
  bf16* vtws = (bf16*)take(big);
  bf16* ctxw = (bf16*)take(big);
  bf16* xtra = (bf16*)take(big);
  // cast buffers alias later-life buffers (dead before vt/attn write them):
  bf16* xq = vtws;  // vtws written only in vt_kernel (after proj)
  bf16* xk = ctxw;  // ctxw written only in attn (after proj)
  bf16* xv = xtra;

  hipLaunchKernelGGL(prep_kernel, dim3(16, 16, 6), dim3(256), 0, stream,
                     Wq, Wk, Wv, Wo, rel_q, rel_k, rel_v,
                     Wtq, Wtk, Wtv, Wto, rqb, rkb, rvt);
  hipLaunchKernelGGL(cast_kernel, dim3((NB * NS * NDM) / (256 * 8), 1, 3), dim3(256), 0, stream,
                     query, key, value, xq, xk, xv);
  hipLaunchKernelGGL(proj_gemm, dim3(8, 256, 3), dim3(256), 0, stream,
                     xq, xk, xv, Wtq, Wtk, Wtv, bq, bk, bv, qws, kws, vws);
  hipLaunchKernelGGL(vt_kernel, dim3(2, 2, NB * NH), dim3(256), 0, stream, vws, vtws);
  hipLaunchKernelGGL(attn_kernel, dim3(NB * NH), dim3(256), 0, stream,
                     qws, kws, vtws, rqb, rkb, rvt, qpos, kvpos, ctxw);
  hipLaunchKernelGGL(out_gemm, dim3(8, 256), dim3(256), 0, stream, ctxw, Wto, bo, out);
}